// Round 14
// baseline (240.294 us; speedup 1.0000x reference)
//
#include <hip/hip_runtime.h>
#include <stdint.h>

#define CC 256
#define NNq 4096

typedef float f32x4 __attribute__((ext_vector_type(4)));
typedef short bf16x8 __attribute__((ext_vector_type(8)));

#define MFMA16(a, b, c) __builtin_amdgcn_mfma_f32_16x16x32_bf16(a, b, c, 0, 0, 0)

static __device__ __forceinline__ short f2bf(float f) {
  unsigned u = __builtin_bit_cast(unsigned, f);
  u += 0x7fffu + ((u >> 16) & 1u);   // RNE
  return (short)(u >> 16);
}
static __device__ __forceinline__ float bf2f(short s) {
  return __builtin_bit_cast(float, ((unsigned)(unsigned short)s) << 16);
}

// ---------------------------------------------------------------------------
// Kernel 1: projections (r12 version — permuted v5 slot order, numerically
// verified in round 12).
//  - q,k: split hi/lo bf16, separate arrays [B][N][32]; q pre-scaled by log2e.
//  - v: bf16 pre-tiled, slot(ml) = [m3 m2 | m4 | m1 m0] within each 32-m
//    chunk — matches the k-dim order of the swapped-E P fragment, so PV
//    consumes P directly from E registers (no LDS/shuffle transpose).
// ---------------------------------------------------------------------------
#define XSTR 66

__global__ __launch_bounds__(256) void proj_kernel(
    const float* __restrict__ x,
    const float* __restrict__ Wq, const float* __restrict__ bq,
    const float* __restrict__ Wk, const float* __restrict__ bk,
    const float* __restrict__ Wv, const float* __restrict__ bv,
    unsigned short* __restrict__ qh_, unsigned short* __restrict__ ql_,
    unsigned short* __restrict__ kh_, unsigned short* __restrict__ kl_,
    unsigned short* __restrict__ v5)
{
  __shared__ float xs[256 * XSTR];
  const int t = threadIdx.x;
  const int b = blockIdx.x >> 6;
  const int n0 = (blockIdx.x & 63) << 6;
  const float L2E = 1.4426950408889634f;

  const float* xb = x + ((size_t)b * CC) * NNq + n0;
#pragma unroll
  for (int i = 0; i < 16; ++i) {
    int fi = i * 256 + t;
    int c = fi >> 4, nv = (fi & 15) << 2;
    float4 v4 = *(const float4*)(xb + (size_t)c * NNq + nv);
    float* d = &xs[c * XSTR + nv];
    d[0] = v4.x; d[1] = v4.y; d[2] = v4.z; d[3] = v4.w;
  }
  __syncthreads();

  const int w = t >> 6, l = t & 63;
  const int l15 = l & 15, l4 = l >> 4;

  f32x4 acc[5][4];
#pragma unroll
  for (int r5 = 0; r5 < 5; ++r5) {
    int rt = w * 5 + r5;
    const float* bias; float bscale;
    if (rt < 16)      { bias = bv + rt * 16;        bscale = 1.f; }
    else if (rt < 18) { bias = bq + (rt - 16) * 16; bscale = L2E; }
    else              { bias = bk + (rt - 18) * 16; bscale = 1.f; }
#pragma unroll
    for (int j = 0; j < 4; ++j) {
      float bval = bias[l4 * 4 + j] * bscale;
#pragma unroll
      for (int nt = 0; nt < 4; ++nt) acc[r5][nt][j] = bval;
    }
  }

#pragma unroll 1
  for (int ks = 0; ks < 8; ++ks) {
    bf16x8 ah[5], al[5];
#pragma unroll
    for (int r5 = 0; r5 < 5; ++r5) {
      int rt = w * 5 + r5;
      const float* wrow; float wscale;
      if (rt < 16)      { wrow = Wv + (size_t)(rt * 16 + l15) * 256;        wscale = 1.f; }
      else if (rt < 18) { wrow = Wq + (size_t)((rt - 16) * 16 + l15) * 256; wscale = L2E; }
      else              { wrow = Wk + (size_t)((rt - 18) * 16 + l15) * 256; wscale = 1.f; }
      const float* src = wrow + ks * 32 + l4 * 8;
#pragma unroll
      for (int i = 0; i < 8; ++i) {
        float v = src[i] * wscale;
        short hh = f2bf(v);
        ah[r5][i] = hh;
        al[r5][i] = f2bf(v - bf2f(hh));
      }
    }
#pragma unroll
    for (int nt = 0; nt < 4; ++nt) {
      bf16x8 bh, bl;
#pragma unroll
      for (int i = 0; i < 8; ++i) {
        float v = xs[(ks * 32 + l4 * 8 + i) * XSTR + nt * 16 + l15];
        short hh = f2bf(v);
        bh[i] = hh;
        bl[i] = f2bf(v - bf2f(hh));
      }
#pragma unroll
      for (int r5 = 0; r5 < 5; ++r5) {
        acc[r5][nt] = MFMA16(ah[r5], bl, acc[r5][nt]);
        acc[r5][nt] = MFMA16(al[r5], bh, acc[r5][nt]);
        acc[r5][nt] = MFMA16(ah[r5], bh, acc[r5][nt]);
      }
    }
  }

#pragma unroll
  for (int r5 = 0; r5 < 5; ++r5) {
    int rt = w * 5 + r5;
#pragma unroll
    for (int nt = 0; nt < 4; ++nt) {
      int n = n0 + nt * 16 + l15;
#pragma unroll
      for (int j = 0; j < 4; ++j) {
        float v = acc[r5][nt][j];
        int sub = l4 * 4 + j;
        if (rt < 16) {
          int c = rt * 16 + sub;
          int ml = n & 31;
          int slot = ((ml >> 2) & 3) * 8 + ((ml >> 4) & 1) * 4 + (ml & 3);
          size_t o = (((size_t)b * 128 + (n >> 5)) * 256 + c) * 32 + slot;
          v5[o] = (unsigned short)f2bf(v);
        } else {
          short hh = f2bf(v);
          short lo = f2bf(v - bf2f(hh));
          unsigned short* dh = (rt < 18) ? qh_ : kh_;
          unsigned short* dl = (rt < 18) ? ql_ : kl_;
          int d = ((rt < 18) ? (rt - 16) : (rt - 18)) * 16 + sub;
          size_t o = ((size_t)b * NNq + n) * 32 + d;
          dh[o] = (unsigned short)hh;
          dl[o] = (unsigned short)lo;
        }
      }
    }
  }
}

// ---------------------------------------------------------------------------
// Kernel 2: fused stats + attention write + PV + epilogue.
// BARRIER-FREE main loop: r10's proven writer (swapped-E, coalesced per-row
// stores, 4.4 TB/s) + in-register P -> PV (permuted v5, r12-verified).
// Block = 256 thr (4 waves) owns (b, 16-n tile); grid 1024.
// Pass 1: wave w sums its 1024-m quarter (swapped-E, fixed shift 64);
//         one __syncthreads; crow per lane-n.
// Pass 2: wave = (ch: 128-c half, mh: 2048-m half); 64 chunks of 32 m:
//   loadV(chunk, own c-half; 8x contiguous 1KB, permuted slots)  [iter-top]
//   loadK(chunk+1)   [1-ahead]
//   E: 6 split-MFMA (A=K rows m, B=Q col n=l15) -> p = exp2(e - crow)
//   ch==0 stores: 2 nontemporal dwordx4 per iter (64B row segments, r10)
//   pack pf -> 8 PV MFMA: acc[ct] += v5[ct] x pf   (k-order matches via slot
//   permutation). E is x2-redundant across ch (measured-cheap; x4 was not).
// In-order vmcnt: PV's wait for vg leaves the (newer) stores in flight.
// End: 2-step LDS merge of mh halves per ch + epilogue.
// ---------------------------------------------------------------------------
__global__ __launch_bounds__(256, 3) void attn_pv_kernel(
    const unsigned short* __restrict__ qh_, const unsigned short* __restrict__ ql_,
    const unsigned short* __restrict__ kh_, const unsigned short* __restrict__ kl_,
    const unsigned short* __restrict__ v5, const float* __restrict__ x,
    const float* __restrict__ gamma, float* __restrict__ out)
{
  __shared__ float sums_lds[4][16];
  __shared__ float mergebuf[2][2048];   // [ch][c128*16 + n16], 16 KB

  const int t = threadIdx.x, w = t >> 6, l = t & 63;
  const int l15 = l & 15, l4 = l >> 4;
  const int sb = ((blockIdx.x & 7) << 7) | (blockIdx.x >> 3);  // 1024%8==0
  const int b = sb >> 8;
  const int n0 = (sb & 255) << 4;

  const unsigned short* khb = kh_ + (size_t)b * NNq * 32;
  const unsigned short* klb = kl_ + (size_t)b * NNq * 32;
  const unsigned short* vbb = v5 + (size_t)b * 1048576;

  // q B-fragment (col n = l15, k = d)
  const size_t qbase = ((size_t)b * NNq + n0 + l15) * 32 + l4 * 8;
  const bf16x8 qbh = *(const bf16x8*)(qh_ + qbase);
  const bf16x8 qbl = *(const bf16x8*)(ql_ + qbase);

  // ---------------- pass 1: row sums over m-quarter w (swapped E) ----------
  float sx = 0.f;
  {
    const int m0 = w * 1024;
    bf16x8 kAh[2], kAl[2];
#pragma unroll
    for (int sub = 0; sub < 2; ++sub) {
      size_t ko = (size_t)(m0 + sub * 16 + l15) * 32 + l4 * 8;
      kAh[sub] = *(const bf16x8*)(khb + ko);
      kAl[sub] = *(const bf16x8*)(klb + ko);
    }
#pragma unroll 1
    for (int it = 0; it < 32; ++it) {
      const int nx = m0 + ((it + 1) & 31) * 32;
      bf16x8 kBh[2], kBl[2];
#pragma unroll
      for (int sub = 0; sub < 2; ++sub) {
        size_t ko = (size_t)(nx + sub * 16 + l15) * 32 + l4 * 8;
        kBh[sub] = *(const bf16x8*)(khb + ko);
        kBl[sub] = *(const bf16x8*)(klb + ko);
      }
#pragma unroll
      for (int sub = 0; sub < 2; ++sub) {
        f32x4 e = {0.f, 0.f, 0.f, 0.f};
        e = MFMA16(kAh[sub], qbl, e);
        e = MFMA16(kAl[sub], qbh, e);
        e = MFMA16(kAh[sub], qbh, e);
#pragma unroll
        for (int j = 0; j < 4; ++j) sx += exp2f(e[j] - 64.0f);
      }
#pragma unroll
      for (int sub = 0; sub < 2; ++sub) { kAh[sub] = kBh[sub]; kAl[sub] = kBl[sub]; }
    }
  }
  sx += __shfl_xor(sx, 16);
  sx += __shfl_xor(sx, 32);
  if (l < 16) sums_lds[w][l] = sx;
  __syncthreads();
  const float crow = 64.0f + log2f(sums_lds[0][l15] + sums_lds[1][l15] +
                                   sums_lds[2][l15] + sums_lds[3][l15]);

  // ---------------- pass 2: barrier-free E + stores + PV ----------------
  const int ch = w & 1, mh = w >> 1;
  const int mbase = mh * 2048;
  const int cbase = ch * 128;

  f32x4 acc[8];   // c = cbase + ct*16 + l4*4 + j ; n = n0 + l15
#pragma unroll
  for (int ct = 0; ct < 8; ++ct) acc[ct] = f32x4{0.f, 0.f, 0.f, 0.f};

  float* arow = out + 8388608 + (size_t)b * NNq * NNq + (size_t)(n0 + l15) * NNq;

  bf16x8 kAh[2], kAl[2];
#pragma unroll
  for (int sub = 0; sub < 2; ++sub) {
    size_t ko = (size_t)(mbase + sub * 16 + l15) * 32 + l4 * 8;
    kAh[sub] = *(const bf16x8*)(khb + ko);
    kAl[sub] = *(const bf16x8*)(klb + ko);
  }

#pragma unroll 1
  for (int it = 0; it < 64; ++it) {
    const int mb = mbase + it * 32;
    // (a) v for THIS chunk — 8x contiguous 1KB, permuted slots; consumed at
    // the end of the iteration (E+exp+store covers L2 latency)
    bf16x8 vg[8];
#pragma unroll
    for (int ct = 0; ct < 8; ++ct) {
      size_t vo = (size_t)(mb >> 5) * 8192 +
                  (size_t)(cbase + ct * 16 + l15) * 32 + l4 * 8;
      vg[ct] = *(const bf16x8*)(vbb + vo);
    }
    // (b) k(chunk+1) prefetch
    const int nx = (it == 63) ? mbase : (mb + 32);
    bf16x8 kBh[2], kBl[2];
#pragma unroll
    for (int sub = 0; sub < 2; ++sub) {
      size_t ko = (size_t)(nx + sub * 16 + l15) * 32 + l4 * 8;
      kBh[sub] = *(const bf16x8*)(khb + ko);
      kBl[sub] = *(const bf16x8*)(klb + ko);
    }
    // (c) E (swapped): e[j] = E[m = mb + sub*16 + l4*4 + j][n = n0 + l15]
    f32x4 p0, p1;
    {
      f32x4 e = {0.f, 0.f, 0.f, 0.f};
      e = MFMA16(kAh[0], qbl, e);
      e = MFMA16(kAl[0], qbh, e);
      e = MFMA16(kAh[0], qbh, e);
#pragma unroll
      for (int j = 0; j < 4; ++j) p0[j] = exp2f(e[j] - crow);
    }
    {
      f32x4 e = {0.f, 0.f, 0.f, 0.f};
      e = MFMA16(kAh[1], qbl, e);
      e = MFMA16(kAl[1], qbh, e);
      e = MFMA16(kAh[1], qbh, e);
#pragma unroll
      for (int j = 0; j < 4; ++j) p1[j] = exp2f(e[j] - crow);
    }
    // (d) attention stores (ch==0 only; r10's proven 64B-segment pattern),
    // issued AFTER the loads -> never forced to drain by a load-wait
    if (ch == 0) {
      float* dst = arow + mb + l4 * 4;
      __builtin_nontemporal_store(p0, (f32x4*)dst);
      __builtin_nontemporal_store(p1, (f32x4*)(dst + 16));
    }
    // (e) pack P -> B-frag (k-slot order matches v5's permuted A-frags)
    bf16x8 pf;
#pragma unroll
    for (int j = 0; j < 4; ++j) {
      pf[j] = f2bf(p0[j]);
      pf[4 + j] = f2bf(p1[j]);
    }
    // (f) PV: 8 MFMA over own c-half
#pragma unroll
    for (int ct = 0; ct < 8; ++ct)
      acc[ct] = MFMA16(vg[ct], pf, acc[ct]);
    // (g) rotate k
#pragma unroll
    for (int sub = 0; sub < 2; ++sub) { kAh[sub] = kBh[sub]; kAl[sub] = kBl[sub]; }
  }

  // ---------------- merge m-halves (per c-half) + epilogue ----------------
  __syncthreads();
  if (mh == 1) {
    float* mb_ = mergebuf[ch];
#pragma unroll
    for (int ct = 0; ct < 8; ++ct)
#pragma unroll
      for (int j = 0; j < 4; ++j)
        mb_[(ct * 16 + l4 * 4 + j) * 16 + l15] = acc[ct][j];
  }
  __syncthreads();
  if (mh == 0) {
    const float gm = gamma[0];
    const float* mb_ = mergebuf[ch];
#pragma unroll
    for (int ct = 0; ct < 8; ++ct) {
#pragma unroll
      for (int j = 0; j < 4; ++j) {
        int c = cbase + ct * 16 + l4 * 4 + j;
        int n = n0 + l15;
        size_t go = ((size_t)b * CC + c) * NNq + n;
        float s = acc[ct][j] + mb_[(ct * 16 + l4 * 4 + j) * 16 + l15];
        float o = s * gm;
        out[4194304 + go] = o;
        out[go] = o + x[go];
      }
    }
  }
}

extern "C" void kernel_launch(void* const* d_in, const int* in_sizes, int n_in,
                              void* d_out, int out_size, void* d_ws, size_t ws_size,
                              hipStream_t stream) {
  const float* x     = (const float*)d_in[0];
  const float* Wq    = (const float*)d_in[1];
  const float* bq    = (const float*)d_in[2];
  const float* Wk    = (const float*)d_in[3];
  const float* bk    = (const float*)d_in[4];
  const float* Wv    = (const float*)d_in[5];
  const float* bv    = (const float*)d_in[6];
  const float* gamma = (const float*)d_in[7];
  float* out = (float*)d_out;

  char* ws = (char*)d_ws;
  unsigned short* qh   = (unsigned short*)(ws);                    // 1 MB
  unsigned short* ql   = (unsigned short*)(ws + (1u << 20));       // 1 MB
  unsigned short* kh   = (unsigned short*)(ws + (2u << 20));       // 1 MB
  unsigned short* kl   = (unsigned short*)(ws + (3u << 20));       // 1 MB
  unsigned short* v5   = (unsigned short*)(ws + (4u << 20));       // 8 MB

  proj_kernel<<<256, 256, 0, stream>>>(x, Wq, bq, Wk, bk, Wv, bv, qh, ql, kh, kl, v5);
  attn_pv_kernel<<<1024, 256, 0, stream>>>(qh, ql, kh, kl, v5, x, gamma, out);
}

// Round 15
// 146.954 us; speedup vs baseline: 1.6352x; 1.6352x over previous
//
#include <hip/hip_runtime.h>
#include <stdint.h>

#define CC 256
#define NNq 4096

typedef float f32x4 __attribute__((ext_vector_type(4)));
typedef short bf16x8 __attribute__((ext_vector_type(8)));

#define MFMA16(a, b, c) __builtin_amdgcn_mfma_f32_16x16x32_bf16(a, b, c, 0, 0, 0)

static __device__ __forceinline__ short f2bf(float f) {
  unsigned u = __builtin_bit_cast(unsigned, f);
  u += 0x7fffu + ((u >> 16) & 1u);   // RNE
  return (short)(u >> 16);
}
static __device__ __forceinline__ float bf2f(short s) {
  return __builtin_bit_cast(float, ((unsigned)(unsigned short)s) << 16);
}

// barrier that does NOT drain vmcnt; sched_barrier(0) fences motion (rule 18).
#define SBAR() do { \
  __builtin_amdgcn_sched_barrier(0); \
  asm volatile("s_waitcnt lgkmcnt(0)" ::: "memory"); \
  __builtin_amdgcn_s_barrier(); \
  __builtin_amdgcn_sched_barrier(0); \
} while (0)

// ---------------------------------------------------------------------------
// Kernel 1: projections (r11/r13 version, v5 standard layout).
//  - q,k: split hi/lo bf16, separate arrays [B][N][32]; q pre-scaled by log2e.
//  - v: bf16 pre-tiled as MFMA A-fragments: v5[b][m>>5][c][m&31].
// ---------------------------------------------------------------------------
#define XSTR 66

__global__ __launch_bounds__(256) void proj_kernel(
    const float* __restrict__ x,
    const float* __restrict__ Wq, const float* __restrict__ bq,
    const float* __restrict__ Wk, const float* __restrict__ bk,
    const float* __restrict__ Wv, const float* __restrict__ bv,
    unsigned short* __restrict__ qh_, unsigned short* __restrict__ ql_,
    unsigned short* __restrict__ kh_, unsigned short* __restrict__ kl_,
    unsigned short* __restrict__ v5)
{
  __shared__ float xs[256 * XSTR];
  const int t = threadIdx.x;
  const int b = blockIdx.x >> 6;
  const int n0 = (blockIdx.x & 63) << 6;
  const float L2E = 1.4426950408889634f;

  const float* xb = x + ((size_t)b * CC) * NNq + n0;
#pragma unroll
  for (int i = 0; i < 16; ++i) {
    int fi = i * 256 + t;
    int c = fi >> 4, nv = (fi & 15) << 2;
    float4 v4 = *(const float4*)(xb + (size_t)c * NNq + nv);
    float* d = &xs[c * XSTR + nv];
    d[0] = v4.x; d[1] = v4.y; d[2] = v4.z; d[3] = v4.w;
  }
  __syncthreads();

  const int w = t >> 6, l = t & 63;
  const int l15 = l & 15, l4 = l >> 4;

  f32x4 acc[5][4];
#pragma unroll
  for (int r5 = 0; r5 < 5; ++r5) {
    int rt = w * 5 + r5;
    const float* bias; float bscale;
    if (rt < 16)      { bias = bv + rt * 16;        bscale = 1.f; }
    else if (rt < 18) { bias = bq + (rt - 16) * 16; bscale = L2E; }
    else              { bias = bk + (rt - 18) * 16; bscale = 1.f; }
#pragma unroll
    for (int j = 0; j < 4; ++j) {
      float bval = bias[l4 * 4 + j] * bscale;
#pragma unroll
      for (int nt = 0; nt < 4; ++nt) acc[r5][nt][j] = bval;
    }
  }

#pragma unroll 1
  for (int ks = 0; ks < 8; ++ks) {
    bf16x8 ah[5], al[5];
#pragma unroll
    for (int r5 = 0; r5 < 5; ++r5) {
      int rt = w * 5 + r5;
      const float* wrow; float wscale;
      if (rt < 16)      { wrow = Wv + (size_t)(rt * 16 + l15) * 256;        wscale = 1.f; }
      else if (rt < 18) { wrow = Wq + (size_t)((rt - 16) * 16 + l15) * 256; wscale = L2E; }
      else              { wrow = Wk + (size_t)((rt - 18) * 16 + l15) * 256; wscale = 1.f; }
      const float* src = wrow + ks * 32 + l4 * 8;
#pragma unroll
      for (int i = 0; i < 8; ++i) {
        float v = src[i] * wscale;
        short hh = f2bf(v);
        ah[r5][i] = hh;
        al[r5][i] = f2bf(v - bf2f(hh));
      }
    }
#pragma unroll
    for (int nt = 0; nt < 4; ++nt) {
      bf16x8 bh, bl;
#pragma unroll
      for (int i = 0; i < 8; ++i) {
        float v = xs[(ks * 32 + l4 * 8 + i) * XSTR + nt * 16 + l15];
        short hh = f2bf(v);
        bh[i] = hh;
        bl[i] = f2bf(v - bf2f(hh));
      }
#pragma unroll
      for (int r5 = 0; r5 < 5; ++r5) {
        acc[r5][nt] = MFMA16(ah[r5], bl, acc[r5][nt]);
        acc[r5][nt] = MFMA16(al[r5], bh, acc[r5][nt]);
        acc[r5][nt] = MFMA16(ah[r5], bh, acc[r5][nt]);
      }
    }
  }

#pragma unroll
  for (int r5 = 0; r5 < 5; ++r5) {
    int rt = w * 5 + r5;
#pragma unroll
    for (int nt = 0; nt < 4; ++nt) {
      int n = n0 + nt * 16 + l15;
#pragma unroll
      for (int j = 0; j < 4; ++j) {
        float v = acc[r5][nt][j];
        int sub = l4 * 4 + j;
        if (rt < 16) {
          int c = rt * 16 + sub;
          size_t o = (((size_t)b * 128 + (n >> 5)) * 256 + c) * 32 + (n & 31);
          v5[o] = (unsigned short)f2bf(v);
        } else {
          short hh = f2bf(v);
          short lo = f2bf(v - bf2f(hh));
          unsigned short* dh = (rt < 18) ? qh_ : kh_;
          unsigned short* dl = (rt < 18) ? ql_ : kl_;
          int d = ((rt < 18) ? (rt - 16) : (rt - 18)) * 16 + sub;
          size_t o = ((size_t)b * NNq + n) * 32 + d;
          dh[o] = (unsigned short)hh;
          dl[o] = (unsigned short)lo;
        }
      }
    }
  }
}

// ---------------------------------------------------------------------------
// Kernel 2: fused stats + attention write + PV + epilogue. PRODUCER/CONSUMER
// with 64-ROW TILES — the measured-best structure (r13: 150.95 us total).
// Block = 1024 thr (16 waves) owns (b, 64 rows); grid 256 = 1 block/CU.
// Pass 1 (all 16 waves): row sums, m-split 16-way (256-m slices).
// Pass 2, per 128-m chunk, ONE SBAR per chunk:
//  waves 0-7 (PRODUCERS: g=pw>>1 row group, h=pw&1 m-half):
//    k 2-ahead, 12 split-E MFMA, 16 exp2, nontemporal attention stores,
//    p -> double-buffered XOR-swizzled [64n][128m] LDS tile.
//  waves 8-15 (CONSUMERS, 32 c each): 8x contiguous-1KB v frags, 16
//    swizzled ds_reads, 32 PV-MFMA (setprio).
// ---------------------------------------------------------------------------
__global__ __launch_bounds__(1024, 4) void attn_pv_kernel(
    const unsigned short* __restrict__ qh_, const unsigned short* __restrict__ ql_,
    const unsigned short* __restrict__ kh_, const unsigned short* __restrict__ kl_,
    const unsigned short* __restrict__ v5, const float* __restrict__ x,
    const float* __restrict__ gamma, float* __restrict__ out)
{
  __shared__ __align__(16) unsigned short p_lds[2][8192]; // [par][64 n][128 m] bf16, XOR-swz
  __shared__ float sums_lds[16][64];

  const int t = threadIdx.x, w = t >> 6, l = t & 63;
  const int l15 = l & 15, l4 = l >> 4;
  const int sb = ((blockIdx.x & 7) << 5) | (blockIdx.x >> 3);  // 256%8==0, bijective
  const int b = sb >> 6;
  const int n0 = (sb & 63) << 6;

  const unsigned short* khb = kh_ + (size_t)b * NNq * 32;
  const unsigned short* klb = kl_ + (size_t)b * NNq * 32;
  const unsigned short* vbb = v5 + (size_t)b * 1048576;
  float* attn = out + 8388608 + (size_t)b * NNq * NNq + (size_t)n0 * NNq;

  // q fragments for all 4 row groups (pass 1 uses all; producers keep own g)
  bf16x8 q4h[4], q4l[4];
#pragma unroll
  for (int rg = 0; rg < 4; ++rg) {
    size_t qo = ((size_t)b * NNq + n0 + rg * 16 + l15) * 32 + l4 * 8;
    q4h[rg] = *(const bf16x8*)(qh_ + qo);
    q4l[rg] = *(const bf16x8*)(ql_ + qo);
  }

  // ---------------- pass 1: row sums; wave owns m in [w*256, w*256+256) -----
  float sx[4][4];
#pragma unroll
  for (int rg = 0; rg < 4; ++rg)
#pragma unroll
    for (int j = 0; j < 4; ++j) sx[rg][j] = 0.f;
  {
    const int mq = w * 256;
    bf16x8 kch[2], kcl[2];
#pragma unroll
    for (int mt = 0; mt < 2; ++mt) {
      size_t ko = (size_t)(mq + mt * 16 + l15) * 32 + l4 * 8;
      kch[mt] = *(const bf16x8*)(khb + ko);
      kcl[mt] = *(const bf16x8*)(klb + ko);
    }
#pragma unroll 1
    for (int it = 0; it < 8; ++it) {
      const int nx = mq + ((it + 1) & 7) * 32;
      bf16x8 knh[2], knl[2];
#pragma unroll
      for (int mt = 0; mt < 2; ++mt) {
        size_t ko = (size_t)(nx + mt * 16 + l15) * 32 + l4 * 8;
        knh[mt] = *(const bf16x8*)(khb + ko);
        knl[mt] = *(const bf16x8*)(klb + ko);
      }
#pragma unroll
      for (int mt = 0; mt < 2; ++mt) {
#pragma unroll
        for (int rg = 0; rg < 4; ++rg) {
          f32x4 e = {0.f, 0.f, 0.f, 0.f};
          e = MFMA16(q4h[rg], kcl[mt], e);
          e = MFMA16(q4l[rg], kch[mt], e);
          e = MFMA16(q4h[rg], kch[mt], e);
#pragma unroll
          for (int j = 0; j < 4; ++j) sx[rg][j] += exp2f(e[j] - 64.0f);
        }
      }
      kch[0] = knh[0]; kch[1] = knh[1];
      kcl[0] = knl[0]; kcl[1] = knl[1];
    }
  }
#pragma unroll
  for (int mask = 1; mask < 16; mask <<= 1)
#pragma unroll
    for (int rg = 0; rg < 4; ++rg)
#pragma unroll
      for (int j = 0; j < 4; ++j) sx[rg][j] += __shfl_xor(sx[rg][j], mask);
  if (l15 == 0) {
#pragma unroll
    for (int rg = 0; rg < 4; ++rg)
#pragma unroll
      for (int j = 0; j < 4; ++j)
        sums_lds[w][rg * 16 + l4 * 4 + j] = sx[rg][j];
  }
  __syncthreads();

  // ---------------- pass 2: role-split pipelined attention + PV -------------
  if (w < 8) {
    // ======================= PRODUCER =======================
    const int g = w >> 1, h = w & 1;
    const bf16x8 qh = q4h[g], qlo = q4l[g];
    f32x4 crow;
#pragma unroll
    for (int j = 0; j < 4; ++j) {
      int r = g * 16 + l4 * 4 + j;
      float S = 0.f;
#pragma unroll
      for (int ww = 0; ww < 16; ++ww) S += sums_lds[ww][r];
      crow[j] = 64.0f + log2f(S);
    }

    bf16x8 kAh[4], kAl[4];
    bf16x8 pwv[2];   // packed p for 4 sub-tiles

    auto loadK = [&](int chunk, bf16x8 (&KH)[4], bf16x8 (&KL)[4]) {
#pragma unroll
      for (int sub = 0; sub < 4; ++sub) {
        size_t ko = (size_t)(chunk * 128 + h * 64 + sub * 16 + l15) * 32 + l4 * 8;
        KH[sub] = *(const bf16x8*)(khb + ko);
        KL[sub] = *(const bf16x8*)(klb + ko);
      }
    };
    auto estep = [&](int ec, const bf16x8 (&KH)[4], const bf16x8 (&KL)[4]) {
#pragma unroll
      for (int sub = 0; sub < 4; ++sub) {
        f32x4 e = {0.f, 0.f, 0.f, 0.f};
        e = MFMA16(qh, KL[sub], e);
        e = MFMA16(qlo, KH[sub], e);
        e = MFMA16(qh, KH[sub], e);
#pragma unroll
        for (int j = 0; j < 4; ++j) {
          float p = exp2f(e[j] - crow[j]);
          int nl = g * 16 + l4 * 4 + j;
          int ml = h * 64 + sub * 16 + l15;
          __builtin_nontemporal_store(p, attn + (size_t)nl * NNq + ec * 128 + ml);
          pwv[sub >> 1][(sub & 1) * 4 + j] = f2bf(p);
        }
      }
    };
    auto pwrite = [&](int par) {
      char* pld = (char*)p_lds[par];
#pragma unroll
      for (int sub = 0; sub < 4; ++sub)
#pragma unroll
        for (int j = 0; j < 4; ++j) {
          int nl = g * 16 + l4 * 4 + j;
          int ml = h * 64 + sub * 16 + l15;
          int byteo = nl * 256 + ((ml * 2) ^ ((nl & 7) << 4));
          *(unsigned short*)(pld + byteo) =
              (unsigned short)pwv[sub >> 1][(sub & 1) * 4 + j];
        }
    };

    loadK(0, kAh, kAl);
    estep(0, kAh, kAl);
    pwrite(0);
    loadK(1, kAh, kAl);

#pragma unroll 1
    for (int it = 0; it < 32; ++it) {
      bf16x8 kBh[4], kBl[4];
      loadK((it + 2) & 31, kBh, kBl);
      if (it < 31) estep(it + 1, kAh, kAl);
      SBAR();
      if (it < 31) pwrite((it + 1) & 1);
#pragma unroll
      for (int sub = 0; sub < 4; ++sub) { kAh[sub] = kBh[sub]; kAl[sub] = kBl[sub]; }
    }
  } else {
    // ======================= CONSUMER =======================
    const int cw = w - 8;   // 32-c slice
    f32x4 acc[2][4];   // c = cw*32 + ct*16 + l4*4 + j ; n = n0 + nt*16 + l15
#pragma unroll
    for (int ct = 0; ct < 2; ++ct)
#pragma unroll
      for (int nt = 0; nt < 4; ++nt) acc[ct][nt] = f32x4{0.f, 0.f, 0.f, 0.f};

    bf16x8 vf[2][4];
    auto vload = [&](int chunk) {
#pragma unroll
      for (int ct = 0; ct < 2; ++ct)
#pragma unroll
        for (int ms = 0; ms < 4; ++ms) {
          size_t vo = (size_t)(chunk * 4 + ms) * 8192 +
                      (size_t)(cw * 32 + ct * 16 + l15) * 32 + l4 * 8;
          vf[ct][ms] = *(const bf16x8*)(vbb + vo);
        }
    };
    vload(0);

#pragma unroll 1
    for (int it = 0; it < 32; ++it) {
      SBAR();
      char* pl = (char*)p_lds[it & 1];
      __builtin_amdgcn_s_setprio(1);
#pragma unroll
      for (int ms = 0; ms < 4; ++ms) {
        int mbyte = ms * 64 + l4 * 16;
        bf16x8 pf[4];
#pragma unroll
        for (int nt = 0; nt < 4; ++nt) {
          int nl = nt * 16 + l15;
          pf[nt] = *(const bf16x8*)(pl + nl * 256 + (mbyte ^ ((nl & 7) << 4)));
        }
#pragma unroll
        for (int ct = 0; ct < 2; ++ct)
#pragma unroll
          for (int nt = 0; nt < 4; ++nt)
            acc[ct][nt] = MFMA16(vf[ct][ms], pf[nt], acc[ct][nt]);
      }
      __builtin_amdgcn_s_setprio(0);
      if (it < 31) vload(it + 1);   // slack = rest of iter + producer E-phase
    }

    // epilogue: weighted = gamma*pv ; final = weighted + x
    const float gm = gamma[0];
#pragma unroll
    for (int ct = 0; ct < 2; ++ct) {
#pragma unroll
      for (int nt = 0; nt < 4; ++nt) {
#pragma unroll
        for (int j = 0; j < 4; ++j) {
          int c = cw * 32 + ct * 16 + l4 * 4 + j;
          int n = n0 + nt * 16 + l15;
          size_t go = ((size_t)b * CC + c) * NNq + n;
          float o = acc[ct][nt][j] * gm;
          out[4194304 + go] = o;
          out[go] = o + x[go];
        }
      }
    }
  }
}

extern "C" void kernel_launch(void* const* d_in, const int* in_sizes, int n_in,
                              void* d_out, int out_size, void* d_ws, size_t ws_size,
                              hipStream_t stream) {
  const float* x     = (const float*)d_in[0];
  const float* Wq    = (const float*)d_in[1];
  const float* bq    = (const float*)d_in[2];
  const float* Wk    = (const float*)d_in[3];
  const float* bk    = (const float*)d_in[4];
  const float* Wv    = (const float*)d_in[5];
  const float* bv    = (const float*)d_in[6];
  const float* gamma = (const float*)d_in[7];
  float* out = (float*)d_out;

  char* ws = (char*)d_ws;
  unsigned short* qh   = (unsigned short*)(ws);                    // 1 MB
  unsigned short* ql   = (unsigned short*)(ws + (1u << 20));       // 1 MB
  unsigned short* kh   = (unsigned short*)(ws + (2u << 20));       // 1 MB
  unsigned short* kl   = (unsigned short*)(ws + (3u << 20));       // 1 MB
  unsigned short* v5   = (unsigned short*)(ws + (4u << 20));       // 8 MB

  proj_kernel<<<256, 256, 0, stream>>>(x, Wq, bq, Wk, bk, Wv, bv, qh, ql, kh, kl, v5);
  attn_pv_kernel<<<256, 1024, 0, stream>>>(qh, ql, kh, kl, v5, x, gamma, out);
}

// Round 16
// 138.987 us; speedup vs baseline: 1.7289x; 1.0573x over previous
//
#include <hip/hip_runtime.h>
#include <stdint.h>

#define CC 256
#define NNq 4096

typedef float f32x4 __attribute__((ext_vector_type(4)));
typedef short bf16x8 __attribute__((ext_vector_type(8)));

#define MFMA16(a, b, c) __builtin_amdgcn_mfma_f32_16x16x32_bf16(a, b, c, 0, 0, 0)

static __device__ __forceinline__ short f2bf(float f) {
  unsigned u = __builtin_bit_cast(unsigned, f);
  u += 0x7fffu + ((u >> 16) & 1u);   // RNE
  return (short)(u >> 16);
}
static __device__ __forceinline__ float bf2f(short s) {
  return __builtin_bit_cast(float, ((unsigned)(unsigned short)s) << 16);
}

// barrier that does NOT drain vmcnt; sched_barrier(0) fences motion (rule 18).
#define SBAR() do { \
  __builtin_amdgcn_sched_barrier(0); \
  asm volatile("s_waitcnt lgkmcnt(0)" ::: "memory"); \
  __builtin_amdgcn_s_barrier(); \
  __builtin_amdgcn_sched_barrier(0); \
} while (0)

// ---------------------------------------------------------------------------
// Kernel 1: projections (r11/r13 version, v5 standard layout).
//  - q,k: split hi/lo bf16, separate arrays [B][N][32]; q pre-scaled by log2e.
//  - v: bf16 pre-tiled as MFMA A-fragments: v5[b][m>>5][c][m&31].
// ---------------------------------------------------------------------------
#define XSTR 66

__global__ __launch_bounds__(256) void proj_kernel(
    const float* __restrict__ x,
    const float* __restrict__ Wq, const float* __restrict__ bq,
    const float* __restrict__ Wk, const float* __restrict__ bk,
    const float* __restrict__ Wv, const float* __restrict__ bv,
    unsigned short* __restrict__ qh_, unsigned short* __restrict__ ql_,
    unsigned short* __restrict__ kh_, unsigned short* __restrict__ kl_,
    unsigned short* __restrict__ v5)
{
  __shared__ float xs[256 * XSTR];
  const int t = threadIdx.x;
  const int b = blockIdx.x >> 6;
  const int n0 = (blockIdx.x & 63) << 6;
  const float L2E = 1.4426950408889634f;

  const float* xb = x + ((size_t)b * CC) * NNq + n0;
#pragma unroll
  for (int i = 0; i < 16; ++i) {
    int fi = i * 256 + t;
    int c = fi >> 4, nv = (fi & 15) << 2;
    float4 v4 = *(const float4*)(xb + (size_t)c * NNq + nv);
    float* d = &xs[c * XSTR + nv];
    d[0] = v4.x; d[1] = v4.y; d[2] = v4.z; d[3] = v4.w;
  }
  __syncthreads();

  const int w = t >> 6, l = t & 63;
  const int l15 = l & 15, l4 = l >> 4;

  f32x4 acc[5][4];
#pragma unroll
  for (int r5 = 0; r5 < 5; ++r5) {
    int rt = w * 5 + r5;
    const float* bias; float bscale;
    if (rt < 16)      { bias = bv + rt * 16;        bscale = 1.f; }
    else if (rt < 18) { bias = bq + (rt - 16) * 16; bscale = L2E; }
    else              { bias = bk + (rt - 18) * 16; bscale = 1.f; }
#pragma unroll
    for (int j = 0; j < 4; ++j) {
      float bval = bias[l4 * 4 + j] * bscale;
#pragma unroll
      for (int nt = 0; nt < 4; ++nt) acc[r5][nt][j] = bval;
    }
  }

#pragma unroll 1
  for (int ks = 0; ks < 8; ++ks) {
    bf16x8 ah[5], al[5];
#pragma unroll
    for (int r5 = 0; r5 < 5; ++r5) {
      int rt = w * 5 + r5;
      const float* wrow; float wscale;
      if (rt < 16)      { wrow = Wv + (size_t)(rt * 16 + l15) * 256;        wscale = 1.f; }
      else if (rt < 18) { wrow = Wq + (size_t)((rt - 16) * 16 + l15) * 256; wscale = L2E; }
      else              { wrow = Wk + (size_t)((rt - 18) * 16 + l15) * 256; wscale = 1.f; }
      const float* src = wrow + ks * 32 + l4 * 8;
#pragma unroll
      for (int i = 0; i < 8; ++i) {
        float v = src[i] * wscale;
        short hh = f2bf(v);
        ah[r5][i] = hh;
        al[r5][i] = f2bf(v - bf2f(hh));
      }
    }
#pragma unroll
    for (int nt = 0; nt < 4; ++nt) {
      bf16x8 bh, bl;
#pragma unroll
      for (int i = 0; i < 8; ++i) {
        float v = xs[(ks * 32 + l4 * 8 + i) * XSTR + nt * 16 + l15];
        short hh = f2bf(v);
        bh[i] = hh;
        bl[i] = f2bf(v - bf2f(hh));
      }
#pragma unroll
      for (int r5 = 0; r5 < 5; ++r5) {
        acc[r5][nt] = MFMA16(ah[r5], bl, acc[r5][nt]);
        acc[r5][nt] = MFMA16(al[r5], bh, acc[r5][nt]);
        acc[r5][nt] = MFMA16(ah[r5], bh, acc[r5][nt]);
      }
    }
  }

#pragma unroll
  for (int r5 = 0; r5 < 5; ++r5) {
    int rt = w * 5 + r5;
#pragma unroll
    for (int nt = 0; nt < 4; ++nt) {
      int n = n0 + nt * 16 + l15;
#pragma unroll
      for (int j = 0; j < 4; ++j) {
        float v = acc[r5][nt][j];
        int sub = l4 * 4 + j;
        if (rt < 16) {
          int c = rt * 16 + sub;
          size_t o = (((size_t)b * 128 + (n >> 5)) * 256 + c) * 32 + (n & 31);
          v5[o] = (unsigned short)f2bf(v);
        } else {
          short hh = f2bf(v);
          short lo = f2bf(v - bf2f(hh));
          unsigned short* dh = (rt < 18) ? qh_ : kh_;
          unsigned short* dl = (rt < 18) ? ql_ : kl_;
          int d = ((rt < 18) ? (rt - 16) : (rt - 18)) * 16 + sub;
          size_t o = ((size_t)b * NNq + n) * 32 + d;
          dh[o] = (unsigned short)hh;
          dl[o] = (unsigned short)lo;
        }
      }
    }
  }
}

// ---------------------------------------------------------------------------
// Kernel 2: fused stats + attention write + PV + epilogue. PRODUCER/CONSUMER
// with 64-ROW TILES (r13 structure, measured best) + REBALANCED ROLES:
// attention stores moved producer -> consumer (from the LDS tile, bf16-
// rounded — r6-verified numerics), upgrading 64B row-segments to full 128B
// lines and cutting the producer's VALU/store stream ~30%.
// Block = 1024 thr (16 waves) owns (b, 64 rows); grid 256 = 1 block/CU.
// Pass 1 (all 16 waves): row sums, m-split 16-way.
// Pass 2, per 128-m chunk, ONE SBAR per chunk:
//  waves 0-7 (PRODUCERS): k 2-ahead, 12 split-E MFMA, 16 exp2, pack ->
//    double-buffered XOR-swizzled [64n][128m] LDS tile. No global stores.
//  waves 8-15 (CONSUMERS, 32 c each): 16 swizzled ds_read_b128 + 32 PV-MFMA
//    (setprio), then vload(it+1), then attention store: 4x ds_read_b64 from
//    the tile -> bf2f -> 4 nontemporal dwordx4 (2 rows x 128B line each).
//    Stores issue after the vloads -> no load-wait ever drains them.
// ---------------------------------------------------------------------------
__global__ __launch_bounds__(1024, 4) void attn_pv_kernel(
    const unsigned short* __restrict__ qh_, const unsigned short* __restrict__ ql_,
    const unsigned short* __restrict__ kh_, const unsigned short* __restrict__ kl_,
    const unsigned short* __restrict__ v5, const float* __restrict__ x,
    const float* __restrict__ gamma, float* __restrict__ out)
{
  __shared__ __align__(16) unsigned short p_lds[2][8192]; // [par][64 n][128 m] bf16, XOR-swz
  __shared__ float sums_lds[16][64];

  const int t = threadIdx.x, w = t >> 6, l = t & 63;
  const int l15 = l & 15, l4 = l >> 4;
  const int sb = ((blockIdx.x & 7) << 5) | (blockIdx.x >> 3);  // 256%8==0, bijective
  const int b = sb >> 6;
  const int n0 = (sb & 63) << 6;

  const unsigned short* khb = kh_ + (size_t)b * NNq * 32;
  const unsigned short* klb = kl_ + (size_t)b * NNq * 32;
  const unsigned short* vbb = v5 + (size_t)b * 1048576;
  float* attn = out + 8388608 + (size_t)b * NNq * NNq + (size_t)n0 * NNq;

  // q fragments for all 4 row groups (pass 1 uses all; producers keep own g)
  bf16x8 q4h[4], q4l[4];
#pragma unroll
  for (int rg = 0; rg < 4; ++rg) {
    size_t qo = ((size_t)b * NNq + n0 + rg * 16 + l15) * 32 + l4 * 8;
    q4h[rg] = *(const bf16x8*)(qh_ + qo);
    q4l[rg] = *(const bf16x8*)(ql_ + qo);
  }

  // ---------------- pass 1: row sums; wave owns m in [w*256, w*256+256) -----
  float sx[4][4];
#pragma unroll
  for (int rg = 0; rg < 4; ++rg)
#pragma unroll
    for (int j = 0; j < 4; ++j) sx[rg][j] = 0.f;
  {
    const int mq = w * 256;
    bf16x8 kch[2], kcl[2];
#pragma unroll
    for (int mt = 0; mt < 2; ++mt) {
      size_t ko = (size_t)(mq + mt * 16 + l15) * 32 + l4 * 8;
      kch[mt] = *(const bf16x8*)(khb + ko);
      kcl[mt] = *(const bf16x8*)(klb + ko);
    }
#pragma unroll 1
    for (int it = 0; it < 8; ++it) {
      const int nx = mq + ((it + 1) & 7) * 32;
      bf16x8 knh[2], knl[2];
#pragma unroll
      for (int mt = 0; mt < 2; ++mt) {
        size_t ko = (size_t)(nx + mt * 16 + l15) * 32 + l4 * 8;
        knh[mt] = *(const bf16x8*)(khb + ko);
        knl[mt] = *(const bf16x8*)(klb + ko);
      }
#pragma unroll
      for (int mt = 0; mt < 2; ++mt) {
#pragma unroll
        for (int rg = 0; rg < 4; ++rg) {
          f32x4 e = {0.f, 0.f, 0.f, 0.f};
          e = MFMA16(q4h[rg], kcl[mt], e);
          e = MFMA16(q4l[rg], kch[mt], e);
          e = MFMA16(q4h[rg], kch[mt], e);
#pragma unroll
          for (int j = 0; j < 4; ++j) sx[rg][j] += exp2f(e[j] - 64.0f);
        }
      }
      kch[0] = knh[0]; kch[1] = knh[1];
      kcl[0] = knl[0]; kcl[1] = knl[1];
    }
  }
#pragma unroll
  for (int mask = 1; mask < 16; mask <<= 1)
#pragma unroll
    for (int rg = 0; rg < 4; ++rg)
#pragma unroll
      for (int j = 0; j < 4; ++j) sx[rg][j] += __shfl_xor(sx[rg][j], mask);
  if (l15 == 0) {
#pragma unroll
    for (int rg = 0; rg < 4; ++rg)
#pragma unroll
      for (int j = 0; j < 4; ++j)
        sums_lds[w][rg * 16 + l4 * 4 + j] = sx[rg][j];
  }
  __syncthreads();

  // ---------------- pass 2: role-split pipelined attention + PV -------------
  if (w < 8) {
    // ======================= PRODUCER =======================
    const int g = w >> 1, h = w & 1;
    const bf16x8 qh = q4h[g], qlo = q4l[g];
    f32x4 crow;
#pragma unroll
    for (int j = 0; j < 4; ++j) {
      int r = g * 16 + l4 * 4 + j;
      float S = 0.f;
#pragma unroll
      for (int ww = 0; ww < 16; ++ww) S += sums_lds[ww][r];
      crow[j] = 64.0f + log2f(S);
    }

    bf16x8 kAh[4], kAl[4];
    bf16x8 pwv[2];   // packed p for 4 sub-tiles

    auto loadK = [&](int chunk, bf16x8 (&KH)[4], bf16x8 (&KL)[4]) {
#pragma unroll
      for (int sub = 0; sub < 4; ++sub) {
        size_t ko = (size_t)(chunk * 128 + h * 64 + sub * 16 + l15) * 32 + l4 * 8;
        KH[sub] = *(const bf16x8*)(khb + ko);
        KL[sub] = *(const bf16x8*)(klb + ko);
      }
    };
    auto estep = [&](const bf16x8 (&KH)[4], const bf16x8 (&KL)[4]) {
#pragma unroll
      for (int sub = 0; sub < 4; ++sub) {
        f32x4 e = {0.f, 0.f, 0.f, 0.f};
        e = MFMA16(qh, KL[sub], e);
        e = MFMA16(qlo, KH[sub], e);
        e = MFMA16(qh, KH[sub], e);
#pragma unroll
        for (int j = 0; j < 4; ++j) {
          float p = exp2f(e[j] - crow[j]);
          pwv[sub >> 1][(sub & 1) * 4 + j] = f2bf(p);
        }
      }
    };
    auto pwrite = [&](int par) {
      char* pld = (char*)p_lds[par];
#pragma unroll
      for (int sub = 0; sub < 4; ++sub)
#pragma unroll
        for (int j = 0; j < 4; ++j) {
          int nl = g * 16 + l4 * 4 + j;
          int ml = h * 64 + sub * 16 + l15;
          int byteo = nl * 256 + ((ml * 2) ^ ((nl & 7) << 4));
          *(unsigned short*)(pld + byteo) =
              (unsigned short)pwv[sub >> 1][(sub & 1) * 4 + j];
        }
    };

    loadK(0, kAh, kAl);
    estep(kAh, kAl);
    pwrite(0);
    loadK(1, kAh, kAl);

#pragma unroll 1
    for (int it = 0; it < 32; ++it) {
      bf16x8 kBh[4], kBl[4];
      loadK((it + 2) & 31, kBh, kBl);
      if (it < 31) estep(kAh, kAl);
      SBAR();
      if (it < 31) pwrite((it + 1) & 1);
#pragma unroll
      for (int sub = 0; sub < 4; ++sub) { kAh[sub] = kBh[sub]; kAl[sub] = kBl[sub]; }
    }
  } else {
    // ======================= CONSUMER =======================
    const int cw = w - 8;   // 32-c slice; also owns 8 attn rows [cw*8, cw*8+8)
    f32x4 acc[2][4];   // c = cw*32 + ct*16 + l4*4 + j ; n = n0 + nt*16 + l15
#pragma unroll
    for (int ct = 0; ct < 2; ++ct)
#pragma unroll
      for (int nt = 0; nt < 4; ++nt) acc[ct][nt] = f32x4{0.f, 0.f, 0.f, 0.f};

    bf16x8 vf[2][4];
    auto vload = [&](int chunk) {
#pragma unroll
      for (int ct = 0; ct < 2; ++ct)
#pragma unroll
        for (int ms = 0; ms < 4; ++ms) {
          size_t vo = (size_t)(chunk * 4 + ms) * 8192 +
                      (size_t)(cw * 32 + ct * 16 + l15) * 32 + l4 * 8;
          vf[ct][ms] = *(const bf16x8*)(vbb + vo);
        }
    };
    vload(0);

#pragma unroll 1
    for (int it = 0; it < 32; ++it) {
      SBAR();
      const int mb = it * 128;
      char* pl = (char*)p_lds[it & 1];
      __builtin_amdgcn_s_setprio(1);
#pragma unroll
      for (int ms = 0; ms < 4; ++ms) {
        int mbyte = ms * 64 + l4 * 16;
        bf16x8 pf[4];
#pragma unroll
        for (int nt = 0; nt < 4; ++nt) {
          int nl = nt * 16 + l15;
          pf[nt] = *(const bf16x8*)(pl + nl * 256 + (mbyte ^ ((nl & 7) << 4)));
        }
#pragma unroll
        for (int ct = 0; ct < 2; ++ct)
#pragma unroll
          for (int nt = 0; nt < 4; ++nt)
            acc[ct][nt] = MFMA16(vf[ct][ms], pf[nt], acc[ct][nt]);
      }
      __builtin_amdgcn_s_setprio(0);
      if (it < 31) vload(it + 1);   // slack = rest of iter + producer E-phase
      // attention store from LDS: rows [cw*8, cw*8+8), all 128 m of this
      // chunk. Per store: 2 rows x full 128B line (lanes 0-31 row A, 32-63
      // row B). Issued AFTER the vloads -> never drained by a load-wait.
#pragma unroll
      for (int s = 0; s < 4; ++s) {
        int row = cw * 8 + s * 2 + (l >> 5);
        int mcol = (l & 31) * 4;
        int byteo = row * 256 + ((mcol * 2) ^ ((row & 7) << 4));
        unsigned long long v64 = *(const unsigned long long*)(pl + byteo);
        f32x4 pv;
#pragma unroll
        for (int i = 0; i < 4; ++i)
          pv[i] = bf2f((short)(unsigned short)(v64 >> (16 * i)));
        __builtin_nontemporal_store(pv,
            (f32x4*)(attn + (size_t)row * NNq + mb + mcol));
      }
    }

    // epilogue: weighted = gamma*pv ; final = weighted + x
    const float gm = gamma[0];
#pragma unroll
    for (int ct = 0; ct < 2; ++ct) {
#pragma unroll
      for (int nt = 0; nt < 4; ++nt) {
#pragma unroll
        for (int j = 0; j < 4; ++j) {
          int c = cw * 32 + ct * 16 + l4 * 4 + j;
          int n = n0 + nt * 16 + l15;
          size_t go = ((size_t)b * CC + c) * NNq + n;
          float o = acc[ct][nt][j] * gm;
          out[4194304 + go] = o;
          out[go] = o + x[go];
        }
      }
    }
  }
}

extern "C" void kernel_launch(void* const* d_in, const int* in_sizes, int n_in,
                              void* d_out, int out_size, void* d_ws, size_t ws_size,
                              hipStream_t stream) {
  const float* x     = (const float*)d_in[0];
  const float* Wq    = (const float*)d_in[1];
  const float* bq    = (const float*)d_in[2];
  const float* Wk    = (const float*)d_in[3];
  const float* bk    = (const float*)d_in[4];
  const float* Wv    = (const float*)d_in[5];
  const float* bv    = (const float*)d_in[6];
  const float* gamma = (const float*)d_in[7];
  float* out = (float*)d_out;

  char* ws = (char*)d_ws;
  unsigned short* qh   = (unsigned short*)(ws);                    // 1 MB
  unsigned short* ql   = (unsigned short*)(ws + (1u << 20));       // 1 MB
  unsigned short* kh   = (unsigned short*)(ws + (2u << 20));       // 1 MB
  unsigned short* kl   = (unsigned short*)(ws + (3u << 20));       // 1 MB
  unsigned short* v5   = (unsigned short*)(ws + (4u << 20));       // 8 MB

  proj_kernel<<<256, 256, 0, stream>>>(x, Wq, bq, Wk, bk, Wv, bv, qh, ql, kh, kl, v5);
  attn_pv_kernel<<<256, 1024, 0, stream>>>(qh, ql, kh, kl, v5, x, gamma, out);
}

// Round 17
// 132.227 us; speedup vs baseline: 1.8173x; 1.0511x over previous
//
#include <hip/hip_runtime.h>
#include <stdint.h>

#define CC 256
#define NNq 4096

typedef float f32x4 __attribute__((ext_vector_type(4)));
typedef short bf16x8 __attribute__((ext_vector_type(8)));

#define MFMA16(a, b, c) __builtin_amdgcn_mfma_f32_16x16x32_bf16(a, b, c, 0, 0, 0)

static __device__ __forceinline__ short f2bf(float f) {
  unsigned u = __builtin_bit_cast(unsigned, f);
  u += 0x7fffu + ((u >> 16) & 1u);   // RNE
  return (short)(u >> 16);
}
static __device__ __forceinline__ float bf2f(short s) {
  return __builtin_bit_cast(float, ((unsigned)(unsigned short)s) << 16);
}

// barrier that does NOT drain vmcnt; sched_barrier(0) fences motion (rule 18).
#define SBAR() do { \
  __builtin_amdgcn_sched_barrier(0); \
  asm volatile("s_waitcnt lgkmcnt(0)" ::: "memory"); \
  __builtin_amdgcn_s_barrier(); \
  __builtin_amdgcn_sched_barrier(0); \
} while (0)

// ---------------------------------------------------------------------------
// Kernel 1: projections (unchanged).
//  - q,k: split hi/lo bf16, separate arrays [B][N][32]; q pre-scaled by log2e.
//  - v: bf16 pre-tiled as MFMA A-fragments: v5[b][m>>5][c][m&31].
// ---------------------------------------------------------------------------
#define XSTR 66

__global__ __launch_bounds__(256) void proj_kernel(
    const float* __restrict__ x,
    const float* __restrict__ Wq, const float* __restrict__ bq,
    const float* __restrict__ Wk, const float* __restrict__ bk,
    const float* __restrict__ Wv, const float* __restrict__ bv,
    unsigned short* __restrict__ qh_, unsigned short* __restrict__ ql_,
    unsigned short* __restrict__ kh_, unsigned short* __restrict__ kl_,
    unsigned short* __restrict__ v5)
{
  __shared__ float xs[256 * XSTR];
  const int t = threadIdx.x;
  const int b = blockIdx.x >> 6;
  const int n0 = (blockIdx.x & 63) << 6;
  const float L2E = 1.4426950408889634f;

  const float* xb = x + ((size_t)b * CC) * NNq + n0;
#pragma unroll
  for (int i = 0; i < 16; ++i) {
    int fi = i * 256 + t;
    int c = fi >> 4, nv = (fi & 15) << 2;
    float4 v4 = *(const float4*)(xb + (size_t)c * NNq + nv);
    float* d = &xs[c * XSTR + nv];
    d[0] = v4.x; d[1] = v4.y; d[2] = v4.z; d[3] = v4.w;
  }
  __syncthreads();

  const int w = t >> 6, l = t & 63;
  const int l15 = l & 15, l4 = l >> 4;

  f32x4 acc[5][4];
#pragma unroll
  for (int r5 = 0; r5 < 5; ++r5) {
    int rt = w * 5 + r5;
    const float* bias; float bscale;
    if (rt < 16)      { bias = bv + rt * 16;        bscale = 1.f; }
    else if (rt < 18) { bias = bq + (rt - 16) * 16; bscale = L2E; }
    else              { bias = bk + (rt - 18) * 16; bscale = 1.f; }
#pragma unroll
    for (int j = 0; j < 4; ++j) {
      float bval = bias[l4 * 4 + j] * bscale;
#pragma unroll
      for (int nt = 0; nt < 4; ++nt) acc[r5][nt][j] = bval;
    }
  }

#pragma unroll 1
  for (int ks = 0; ks < 8; ++ks) {
    bf16x8 ah[5], al[5];
#pragma unroll
    for (int r5 = 0; r5 < 5; ++r5) {
      int rt = w * 5 + r5;
      const float* wrow; float wscale;
      if (rt < 16)      { wrow = Wv + (size_t)(rt * 16 + l15) * 256;        wscale = 1.f; }
      else if (rt < 18) { wrow = Wq + (size_t)((rt - 16) * 16 + l15) * 256; wscale = L2E; }
      else              { wrow = Wk + (size_t)((rt - 18) * 16 + l15) * 256; wscale = 1.f; }
      const float* src = wrow + ks * 32 + l4 * 8;
#pragma unroll
      for (int i = 0; i < 8; ++i) {
        float v = src[i] * wscale;
        short hh = f2bf(v);
        ah[r5][i] = hh;
        al[r5][i] = f2bf(v - bf2f(hh));
      }
    }
#pragma unroll
    for (int nt = 0; nt < 4; ++nt) {
      bf16x8 bh, bl;
#pragma unroll
      for (int i = 0; i < 8; ++i) {
        float v = xs[(ks * 32 + l4 * 8 + i) * XSTR + nt * 16 + l15];
        short hh = f2bf(v);
        bh[i] = hh;
        bl[i] = f2bf(v - bf2f(hh));
      }
#pragma unroll
      for (int r5 = 0; r5 < 5; ++r5) {
        acc[r5][nt] = MFMA16(ah[r5], bl, acc[r5][nt]);
        acc[r5][nt] = MFMA16(al[r5], bh, acc[r5][nt]);
        acc[r5][nt] = MFMA16(ah[r5], bh, acc[r5][nt]);
      }
    }
  }

#pragma unroll
  for (int r5 = 0; r5 < 5; ++r5) {
    int rt = w * 5 + r5;
#pragma unroll
    for (int nt = 0; nt < 4; ++nt) {
      int n = n0 + nt * 16 + l15;
#pragma unroll
      for (int j = 0; j < 4; ++j) {
        float v = acc[r5][nt][j];
        int sub = l4 * 4 + j;
        if (rt < 16) {
          int c = rt * 16 + sub;
          size_t o = (((size_t)b * 128 + (n >> 5)) * 256 + c) * 32 + (n & 31);
          v5[o] = (unsigned short)f2bf(v);
        } else {
          short hh = f2bf(v);
          short lo = f2bf(v - bf2f(hh));
          unsigned short* dh = (rt < 18) ? qh_ : kh_;
          unsigned short* dl = (rt < 18) ? ql_ : kl_;
          int d = ((rt < 18) ? (rt - 16) : (rt - 18)) * 16 + sub;
          size_t o = ((size_t)b * NNq + n) * 32 + d;
          dh[o] = (unsigned short)hh;
          dl[o] = (unsigned short)lo;
        }
      }
    }
  }
}

// ---------------------------------------------------------------------------
// Kernel 2: fused stats + attention write + PV + epilogue. PRODUCER/CONSUMER,
// 64-row tiles (r13/r16 structure) + SWAPPED-E PRODUCER:
// producer MFMA is (A=K, B=Q) [r10-verified orientation] so each lane holds
// P for ONE attention row (n = l15) and 4 CONSECUTIVE m -> crow is a scalar
// and the LDS publish is one packed ds_write_b64 per sub-tile (16 u16 writes
// -> 4 b64 writes). Consumer side / tile layout / reads unchanged (r16).
// Block = 1024 thr (16 waves) owns (b, 64 rows); grid 256 = 1 block/CU.
// ---------------------------------------------------------------------------
__global__ __launch_bounds__(1024, 4) void attn_pv_kernel(
    const unsigned short* __restrict__ qh_, const unsigned short* __restrict__ ql_,
    const unsigned short* __restrict__ kh_, const unsigned short* __restrict__ kl_,
    const unsigned short* __restrict__ v5, const float* __restrict__ x,
    const float* __restrict__ gamma, float* __restrict__ out)
{
  __shared__ __align__(16) unsigned short p_lds[2][8192]; // [par][64 n][128 m] bf16, XOR-swz
  __shared__ float sums_lds[16][64];

  const int t = threadIdx.x, w = t >> 6, l = t & 63;
  const int l15 = l & 15, l4 = l >> 4;
  const int sb = ((blockIdx.x & 7) << 5) | (blockIdx.x >> 3);  // 256%8==0, bijective
  const int b = sb >> 6;
  const int n0 = (sb & 63) << 6;

  const unsigned short* khb = kh_ + (size_t)b * NNq * 32;
  const unsigned short* klb = kl_ + (size_t)b * NNq * 32;
  const unsigned short* vbb = v5 + (size_t)b * 1048576;
  float* attn = out + 8388608 + (size_t)b * NNq * NNq + (size_t)n0 * NNq;

  // q fragments for all 4 row groups (pass 1 uses all; producers keep own g)
  bf16x8 q4h[4], q4l[4];
#pragma unroll
  for (int rg = 0; rg < 4; ++rg) {
    size_t qo = ((size_t)b * NNq + n0 + rg * 16 + l15) * 32 + l4 * 8;
    q4h[rg] = *(const bf16x8*)(qh_ + qo);
    q4l[rg] = *(const bf16x8*)(ql_ + qo);
  }

  // ---------------- pass 1: row sums; wave owns m in [w*256, w*256+256) -----
  float sx[4][4];
#pragma unroll
  for (int rg = 0; rg < 4; ++rg)
#pragma unroll
    for (int j = 0; j < 4; ++j) sx[rg][j] = 0.f;
  {
    const int mq = w * 256;
    bf16x8 kch[2], kcl[2];
#pragma unroll
    for (int mt = 0; mt < 2; ++mt) {
      size_t ko = (size_t)(mq + mt * 16 + l15) * 32 + l4 * 8;
      kch[mt] = *(const bf16x8*)(khb + ko);
      kcl[mt] = *(const bf16x8*)(klb + ko);
    }
#pragma unroll 1
    for (int it = 0; it < 8; ++it) {
      const int nx = mq + ((it + 1) & 7) * 32;
      bf16x8 knh[2], knl[2];
#pragma unroll
      for (int mt = 0; mt < 2; ++mt) {
        size_t ko = (size_t)(nx + mt * 16 + l15) * 32 + l4 * 8;
        knh[mt] = *(const bf16x8*)(khb + ko);
        knl[mt] = *(const bf16x8*)(klb + ko);
      }
#pragma unroll
      for (int mt = 0; mt < 2; ++mt) {
#pragma unroll
        for (int rg = 0; rg < 4; ++rg) {
          f32x4 e = {0.f, 0.f, 0.f, 0.f};
          e = MFMA16(q4h[rg], kcl[mt], e);
          e = MFMA16(q4l[rg], kch[mt], e);
          e = MFMA16(q4h[rg], kch[mt], e);
#pragma unroll
          for (int j = 0; j < 4; ++j) sx[rg][j] += exp2f(e[j] - 64.0f);
        }
      }
      kch[0] = knh[0]; kch[1] = knh[1];
      kcl[0] = knl[0]; kcl[1] = knl[1];
    }
  }
#pragma unroll
  for (int mask = 1; mask < 16; mask <<= 1)
#pragma unroll
    for (int rg = 0; rg < 4; ++rg)
#pragma unroll
      for (int j = 0; j < 4; ++j) sx[rg][j] += __shfl_xor(sx[rg][j], mask);
  if (l15 == 0) {
#pragma unroll
    for (int rg = 0; rg < 4; ++rg)
#pragma unroll
      for (int j = 0; j < 4; ++j)
        sums_lds[w][rg * 16 + l4 * 4 + j] = sx[rg][j];
  }
  __syncthreads();

  // ---------------- pass 2: role-split pipelined attention + PV -------------
  if (w < 8) {
    // ======================= PRODUCER (swapped-E) =======================
    const int g = w >> 1, h = w & 1;
    const bf16x8 qbh = q4h[g], qbl = q4l[g];   // B-operand: col n = l15
    // crow is a SCALAR: this lane's attention row is n = n0 + g*16 + l15
    float crn;
    {
      float S = 0.f;
#pragma unroll
      for (int ww = 0; ww < 16; ++ww) S += sums_lds[ww][g * 16 + l15];
      crn = 64.0f + log2f(S);
    }

    bf16x8 kAh[4], kAl[4];
    unsigned long long pwu[4];   // packed p: per sub, 4 consecutive m @ row l15

    auto loadK = [&](int chunk, bf16x8 (&KH)[4], bf16x8 (&KL)[4]) {
#pragma unroll
      for (int sub = 0; sub < 4; ++sub) {
        size_t ko = (size_t)(chunk * 128 + h * 64 + sub * 16 + l15) * 32 + l4 * 8;
        KH[sub] = *(const bf16x8*)(khb + ko);
        KL[sub] = *(const bf16x8*)(klb + ko);
      }
    };
    // swapped: e[j] = E[m = h*64 + sub*16 + l4*4 + j][n = n0 + g*16 + l15]
    auto estep = [&](const bf16x8 (&KH)[4], const bf16x8 (&KL)[4]) {
#pragma unroll
      for (int sub = 0; sub < 4; ++sub) {
        f32x4 e = {0.f, 0.f, 0.f, 0.f};
        e = MFMA16(KH[sub], qbl, e);
        e = MFMA16(KL[sub], qbh, e);
        e = MFMA16(KH[sub], qbh, e);
        unsigned w0 = ((unsigned)(unsigned short)f2bf(exp2f(e[1] - crn)) << 16)
                    |  (unsigned)(unsigned short)f2bf(exp2f(e[0] - crn));
        unsigned w1 = ((unsigned)(unsigned short)f2bf(exp2f(e[3] - crn)) << 16)
                    |  (unsigned)(unsigned short)f2bf(exp2f(e[2] - crn));
        pwu[sub] = ((unsigned long long)w1 << 32) | w0;
      }
    };
    auto pwrite = [&](int par) {
      char* pld = (char*)p_lds[par];
      const int nl = g * 16 + l15;
#pragma unroll
      for (int sub = 0; sub < 4; ++sub) {
        int ml = h * 64 + sub * 16 + l4 * 4;   // 4 consecutive m, 8-aligned span
        int byteo = nl * 256 + ((ml * 2) ^ ((nl & 7) << 4));
        *(unsigned long long*)(pld + byteo) = pwu[sub];
      }
    };

    loadK(0, kAh, kAl);
    estep(kAh, kAl);
    pwrite(0);
    loadK(1, kAh, kAl);

#pragma unroll 1
    for (int it = 0; it < 32; ++it) {
      bf16x8 kBh[4], kBl[4];
      loadK((it + 2) & 31, kBh, kBl);
      if (it < 31) estep(kAh, kAl);
      SBAR();
      if (it < 31) pwrite((it + 1) & 1);
#pragma unroll
      for (int sub = 0; sub < 4; ++sub) { kAh[sub] = kBh[sub]; kAl[sub] = kBl[sub]; }
    }
  } else {
    // ======================= CONSUMER (r16 verbatim) =======================
    const int cw = w - 8;   // 32-c slice; also owns 8 attn rows [cw*8, cw*8+8)
    f32x4 acc[2][4];   // c = cw*32 + ct*16 + l4*4 + j ; n = n0 + nt*16 + l15
#pragma unroll
    for (int ct = 0; ct < 2; ++ct)
#pragma unroll
      for (int nt = 0; nt < 4; ++nt) acc[ct][nt] = f32x4{0.f, 0.f, 0.f, 0.f};

    bf16x8 vf[2][4];
    auto vload = [&](int chunk) {
#pragma unroll
      for (int ct = 0; ct < 2; ++ct)
#pragma unroll
        for (int ms = 0; ms < 4; ++ms) {
          size_t vo = (size_t)(chunk * 4 + ms) * 8192 +
                      (size_t)(cw * 32 + ct * 16 + l15) * 32 + l4 * 8;
          vf[ct][ms] = *(const bf16x8*)(vbb + vo);
        }
    };
    vload(0);

#pragma unroll 1
    for (int it = 0; it < 32; ++it) {
      SBAR();
      const int mb = it * 128;
      char* pl = (char*)p_lds[it & 1];
      __builtin_amdgcn_s_setprio(1);
#pragma unroll
      for (int ms = 0; ms < 4; ++ms) {
        int mbyte = ms * 64 + l4 * 16;
        bf16x8 pf[4];
#pragma unroll
        for (int nt = 0; nt < 4; ++nt) {
          int nl = nt * 16 + l15;
          pf[nt] = *(const bf16x8*)(pl + nl * 256 + (mbyte ^ ((nl & 7) << 4)));
        }
#pragma unroll
        for (int ct = 0; ct < 2; ++ct)
#pragma unroll
          for (int nt = 0; nt < 4; ++nt)
            acc[ct][nt] = MFMA16(vf[ct][ms], pf[nt], acc[ct][nt]);
      }
      __builtin_amdgcn_s_setprio(0);
      if (it < 31) vload(it + 1);   // slack = rest of iter + producer E-phase
      // attention store from LDS: rows [cw*8, cw*8+8), all 128 m of this
      // chunk. Per store: 2 rows x full 128B line. Issued AFTER the vloads.
#pragma unroll
      for (int s = 0; s < 4; ++s) {
        int row = cw * 8 + s * 2 + (l >> 5);
        int mcol = (l & 31) * 4;
        int byteo = row * 256 + ((mcol * 2) ^ ((row & 7) << 4));
        unsigned long long v64 = *(const unsigned long long*)(pl + byteo);
        f32x4 pv;
#pragma unroll
        for (int i = 0; i < 4; ++i)
          pv[i] = bf2f((short)(unsigned short)(v64 >> (16 * i)));
        __builtin_nontemporal_store(pv,
            (f32x4*)(attn + (size_t)row * NNq + mb + mcol));
      }
    }

    // epilogue: weighted = gamma*pv ; final = weighted + x
    const float gm = gamma[0];
#pragma unroll
    for (int ct = 0; ct < 2; ++ct) {
#pragma unroll
      for (int nt = 0; nt < 4; ++nt) {
#pragma unroll
        for (int j = 0; j < 4; ++j) {
          int c = cw * 32 + ct * 16 + l4 * 4 + j;
          int n = n0 + nt * 16 + l15;
          size_t go = ((size_t)b * CC + c) * NNq + n;
          float o = acc[ct][nt][j] * gm;
          out[4194304 + go] = o;
          out[go] = o + x[go];
        }
      }
    }
  }
}

extern "C" void kernel_launch(void* const* d_in, const int* in_sizes, int n_in,
                              void* d_out, int out_size, void* d_ws, size_t ws_size,
                              hipStream_t stream) {
  const float* x     = (const float*)d_in[0];
  const float* Wq    = (const float*)d_in[1];
  const float* bq    = (const float*)d_in[2];
  const float* Wk    = (const float*)d_in[3];
  const float* bk    = (const float*)d_in[4];
  const float* Wv    = (const float*)d_in[5];
  const float* bv    = (const float*)d_in[6];
  const float* gamma = (const float*)d_in[7];
  float* out = (float*)d_out;

  char* ws = (char*)d_ws;
  unsigned short* qh   = (unsigned short*)(ws);                    // 1 MB
  unsigned short* ql   = (unsigned short*)(ws + (1u << 20));       // 1 MB
  unsigned short* kh   = (unsigned short*)(ws + (2u << 20));       // 1 MB
  unsigned short* kl   = (unsigned short*)(ws + (3u << 20));       // 1 MB
  unsigned short* v5   = (unsigned short*)(ws + (4u << 20));       // 8 MB

  proj_kernel<<<256, 256, 0, stream>>>(x, Wq, bq, Wk, bk, Wv, bv, qh, ql, kh, kl, v5);
  attn_pv_kernel<<<256, 1024, 0, stream>>>(qh, ql, kh, kl, v5, x, gamma, out);
}

// Round 18
// 131.526 us; speedup vs baseline: 1.8270x; 1.0053x over previous
//
#include <hip/hip_runtime.h>
#include <stdint.h>

#define CC 256
#define NNq 4096

typedef float f32x4 __attribute__((ext_vector_type(4)));
typedef short bf16x8 __attribute__((ext_vector_type(8)));

#define MFMA16(a, b, c) __builtin_amdgcn_mfma_f32_16x16x32_bf16(a, b, c, 0, 0, 0)

static __device__ __forceinline__ short f2bf(float f) {
  unsigned u = __builtin_bit_cast(unsigned, f);
  u += 0x7fffu + ((u >> 16) & 1u);   // RNE
  return (short)(u >> 16);
}
static __device__ __forceinline__ float bf2f(short s) {
  return __builtin_bit_cast(float, ((unsigned)(unsigned short)s) << 16);
}

// barrier that does NOT drain vmcnt; sched_barrier(0) fences motion (rule 18).
#define SBAR() do { \
  __builtin_amdgcn_sched_barrier(0); \
  asm volatile("s_waitcnt lgkmcnt(0)" ::: "memory"); \
  __builtin_amdgcn_s_barrier(); \
  __builtin_amdgcn_sched_barrier(0); \
} while (0)

// ---------------------------------------------------------------------------
// Kernel 1: projections (unchanged).
//  - q,k: split hi/lo bf16, separate arrays [B][N][32]; q pre-scaled by log2e.
//  - v: bf16 pre-tiled as MFMA A-fragments: v5[b][m>>5][c][m&31].
// ---------------------------------------------------------------------------
#define XSTR 66

__global__ __launch_bounds__(256) void proj_kernel(
    const float* __restrict__ x,
    const float* __restrict__ Wq, const float* __restrict__ bq,
    const float* __restrict__ Wk, const float* __restrict__ bk,
    const float* __restrict__ Wv, const float* __restrict__ bv,
    unsigned short* __restrict__ qh_, unsigned short* __restrict__ ql_,
    unsigned short* __restrict__ kh_, unsigned short* __restrict__ kl_,
    unsigned short* __restrict__ v5)
{
  __shared__ float xs[256 * XSTR];
  const int t = threadIdx.x;
  const int b = blockIdx.x >> 6;
  const int n0 = (blockIdx.x & 63) << 6;
  const float L2E = 1.4426950408889634f;

  const float* xb = x + ((size_t)b * CC) * NNq + n0;
#pragma unroll
  for (int i = 0; i < 16; ++i) {
    int fi = i * 256 + t;
    int c = fi >> 4, nv = (fi & 15) << 2;
    float4 v4 = *(const float4*)(xb + (size_t)c * NNq + nv);
    float* d = &xs[c * XSTR + nv];
    d[0] = v4.x; d[1] = v4.y; d[2] = v4.z; d[3] = v4.w;
  }
  __syncthreads();

  const int w = t >> 6, l = t & 63;
  const int l15 = l & 15, l4 = l >> 4;

  f32x4 acc[5][4];
#pragma unroll
  for (int r5 = 0; r5 < 5; ++r5) {
    int rt = w * 5 + r5;
    const float* bias; float bscale;
    if (rt < 16)      { bias = bv + rt * 16;        bscale = 1.f; }
    else if (rt < 18) { bias = bq + (rt - 16) * 16; bscale = L2E; }
    else              { bias = bk + (rt - 18) * 16; bscale = 1.f; }
#pragma unroll
    for (int j = 0; j < 4; ++j) {
      float bval = bias[l4 * 4 + j] * bscale;
#pragma unroll
      for (int nt = 0; nt < 4; ++nt) acc[r5][nt][j] = bval;
    }
  }

#pragma unroll 1
  for (int ks = 0; ks < 8; ++ks) {
    bf16x8 ah[5], al[5];
#pragma unroll
    for (int r5 = 0; r5 < 5; ++r5) {
      int rt = w * 5 + r5;
      const float* wrow; float wscale;
      if (rt < 16)      { wrow = Wv + (size_t)(rt * 16 + l15) * 256;        wscale = 1.f; }
      else if (rt < 18) { wrow = Wq + (size_t)((rt - 16) * 16 + l15) * 256; wscale = L2E; }
      else              { wrow = Wk + (size_t)((rt - 18) * 16 + l15) * 256; wscale = 1.f; }
      const float* src = wrow + ks * 32 + l4 * 8;
#pragma unroll
      for (int i = 0; i < 8; ++i) {
        float v = src[i] * wscale;
        short hh = f2bf(v);
        ah[r5][i] = hh;
        al[r5][i] = f2bf(v - bf2f(hh));
      }
    }
#pragma unroll
    for (int nt = 0; nt < 4; ++nt) {
      bf16x8 bh, bl;
#pragma unroll
      for (int i = 0; i < 8; ++i) {
        float v = xs[(ks * 32 + l4 * 8 + i) * XSTR + nt * 16 + l15];
        short hh = f2bf(v);
        bh[i] = hh;
        bl[i] = f2bf(v - bf2f(hh));
      }
#pragma unroll
      for (int r5 = 0; r5 < 5; ++r5) {
        acc[r5][nt] = MFMA16(ah[r5], bl, acc[r5][nt]);
        acc[r5][nt] = MFMA16(al[r5], bh, acc[r5][nt]);
        acc[r5][nt] = MFMA16(ah[r5], bh, acc[r5][nt]);
      }
    }
  }

#pragma unroll
  for (int r5 = 0; r5 < 5; ++r5) {
    int rt = w * 5 + r5;
#pragma unroll
    for (int nt = 0; nt < 4; ++nt) {
      int n = n0 + nt * 16 + l15;
#pragma unroll
      for (int j = 0; j < 4; ++j) {
        float v = acc[r5][nt][j];
        int sub = l4 * 4 + j;
        if (rt < 16) {
          int c = rt * 16 + sub;
          size_t o = (((size_t)b * 128 + (n >> 5)) * 256 + c) * 32 + (n & 31);
          v5[o] = (unsigned short)f2bf(v);
        } else {
          short hh = f2bf(v);
          short lo = f2bf(v - bf2f(hh));
          unsigned short* dh = (rt < 18) ? qh_ : kh_;
          unsigned short* dl = (rt < 18) ? ql_ : kl_;
          int d = ((rt < 18) ? (rt - 16) : (rt - 18)) * 16 + sub;
          size_t o = ((size_t)b * NNq + n) * 32 + d;
          dh[o] = (unsigned short)hh;
          dl[o] = (unsigned short)lo;
        }
      }
    }
  }
}

// ---------------------------------------------------------------------------
// Kernel 2: fused stats + attention write + PV + epilogue. PRODUCER/CONSUMER,
// 64-row tiles, swapped-E producer (r17) + two producer VALU cuts:
//  (1) -crn (and pass-1's -64) folded into the MFMA C-init — the shift rides
//      the matrix pipe's A*B+C for free (16 v_sub/iter removed).
//  (2) p-pack via v_cvt_pk_bf16_f32 (T12 recipe): 16 manual-RNE f2bf (48
//      VALU) + 4 ORs -> 8 cvt_pk instructions.
// Consumer / tile / barrier protocol unchanged (r16/r17).
// Block = 1024 thr (16 waves) owns (b, 64 rows); grid 256 = 1 block/CU.
// ---------------------------------------------------------------------------
__global__ __launch_bounds__(1024, 4) void attn_pv_kernel(
    const unsigned short* __restrict__ qh_, const unsigned short* __restrict__ ql_,
    const unsigned short* __restrict__ kh_, const unsigned short* __restrict__ kl_,
    const unsigned short* __restrict__ v5, const float* __restrict__ x,
    const float* __restrict__ gamma, float* __restrict__ out)
{
  __shared__ __align__(16) unsigned short p_lds[2][8192]; // [par][64 n][128 m] bf16, XOR-swz
  __shared__ float sums_lds[16][64];

  const int t = threadIdx.x, w = t >> 6, l = t & 63;
  const int l15 = l & 15, l4 = l >> 4;
  const int sb = ((blockIdx.x & 7) << 5) | (blockIdx.x >> 3);  // 256%8==0, bijective
  const int b = sb >> 6;
  const int n0 = (sb & 63) << 6;

  const unsigned short* khb = kh_ + (size_t)b * NNq * 32;
  const unsigned short* klb = kl_ + (size_t)b * NNq * 32;
  const unsigned short* vbb = v5 + (size_t)b * 1048576;
  float* attn = out + 8388608 + (size_t)b * NNq * NNq + (size_t)n0 * NNq;

  // q fragments for all 4 row groups (pass 1 uses all; producers keep own g)
  bf16x8 q4h[4], q4l[4];
#pragma unroll
  for (int rg = 0; rg < 4; ++rg) {
    size_t qo = ((size_t)b * NNq + n0 + rg * 16 + l15) * 32 + l4 * 8;
    q4h[rg] = *(const bf16x8*)(qh_ + qo);
    q4l[rg] = *(const bf16x8*)(ql_ + qo);
  }

  // ---------------- pass 1: row sums; wave owns m in [w*256, w*256+256) -----
  float sx[4][4];
#pragma unroll
  for (int rg = 0; rg < 4; ++rg)
#pragma unroll
    for (int j = 0; j < 4; ++j) sx[rg][j] = 0.f;
  {
    const int mq = w * 256;
    bf16x8 kch[2], kcl[2];
#pragma unroll
    for (int mt = 0; mt < 2; ++mt) {
      size_t ko = (size_t)(mq + mt * 16 + l15) * 32 + l4 * 8;
      kch[mt] = *(const bf16x8*)(khb + ko);
      kcl[mt] = *(const bf16x8*)(klb + ko);
    }
#pragma unroll 1
    for (int it = 0; it < 8; ++it) {
      const int nx = mq + ((it + 1) & 7) * 32;
      bf16x8 knh[2], knl[2];
#pragma unroll
      for (int mt = 0; mt < 2; ++mt) {
        size_t ko = (size_t)(nx + mt * 16 + l15) * 32 + l4 * 8;
        knh[mt] = *(const bf16x8*)(khb + ko);
        knl[mt] = *(const bf16x8*)(klb + ko);
      }
#pragma unroll
      for (int mt = 0; mt < 2; ++mt) {
#pragma unroll
        for (int rg = 0; rg < 4; ++rg) {
          f32x4 e = {-64.f, -64.f, -64.f, -64.f};   // shift folded into C-init
          e = MFMA16(q4h[rg], kcl[mt], e);
          e = MFMA16(q4l[rg], kch[mt], e);
          e = MFMA16(q4h[rg], kch[mt], e);
#pragma unroll
          for (int j = 0; j < 4; ++j) sx[rg][j] += exp2f(e[j]);
        }
      }
      kch[0] = knh[0]; kch[1] = knh[1];
      kcl[0] = knl[0]; kcl[1] = knl[1];
    }
  }
#pragma unroll
  for (int mask = 1; mask < 16; mask <<= 1)
#pragma unroll
    for (int rg = 0; rg < 4; ++rg)
#pragma unroll
      for (int j = 0; j < 4; ++j) sx[rg][j] += __shfl_xor(sx[rg][j], mask);
  if (l15 == 0) {
#pragma unroll
    for (int rg = 0; rg < 4; ++rg)
#pragma unroll
      for (int j = 0; j < 4; ++j)
        sums_lds[w][rg * 16 + l4 * 4 + j] = sx[rg][j];
  }
  __syncthreads();

  // ---------------- pass 2: role-split pipelined attention + PV -------------
  if (w < 8) {
    // ======================= PRODUCER (swapped-E) =======================
    const int g = w >> 1, h = w & 1;
    const bf16x8 qbh = q4h[g], qbl = q4l[g];   // B-operand: col n = l15
    // crow is a SCALAR: this lane's attention row is n = n0 + g*16 + l15
    float ncrn;   // negative crow, folded into the MFMA C-init
    {
      float S = 0.f;
#pragma unroll
      for (int ww = 0; ww < 16; ++ww) S += sums_lds[ww][g * 16 + l15];
      ncrn = -(64.0f + log2f(S));
    }

    bf16x8 kAh[4], kAl[4];
    unsigned long long pwu[4];   // packed p: per sub, 4 consecutive m @ row l15

    auto loadK = [&](int chunk, bf16x8 (&KH)[4], bf16x8 (&KL)[4]) {
#pragma unroll
      for (int sub = 0; sub < 4; ++sub) {
        size_t ko = (size_t)(chunk * 128 + h * 64 + sub * 16 + l15) * 32 + l4 * 8;
        KH[sub] = *(const bf16x8*)(khb + ko);
        KL[sub] = *(const bf16x8*)(klb + ko);
      }
    };
    // swapped: e[j] = E[m = h*64 + sub*16 + l4*4 + j][n = n0 + g*16 + l15] - crn
    auto estep = [&](const bf16x8 (&KH)[4], const bf16x8 (&KL)[4]) {
#pragma unroll
      for (int sub = 0; sub < 4; ++sub) {
        f32x4 e = {ncrn, ncrn, ncrn, ncrn};
        e = MFMA16(KH[sub], qbl, e);
        e = MFMA16(KL[sub], qbh, e);
        e = MFMA16(KH[sub], qbh, e);
        float p0 = exp2f(e[0]), p1 = exp2f(e[1]);
        float p2 = exp2f(e[2]), p3 = exp2f(e[3]);
        unsigned w0, w1;
        asm("v_cvt_pk_bf16_f32 %0, %1, %2" : "=v"(w0) : "v"(p0), "v"(p1));
        asm("v_cvt_pk_bf16_f32 %0, %1, %2" : "=v"(w1) : "v"(p2), "v"(p3));
        pwu[sub] = ((unsigned long long)w1 << 32) | w0;
      }
    };
    auto pwrite = [&](int par) {
      char* pld = (char*)p_lds[par];
      const int nl = g * 16 + l15;
#pragma unroll
      for (int sub = 0; sub < 4; ++sub) {
        int ml = h * 64 + sub * 16 + l4 * 4;   // 4 consecutive m, 8-aligned span
        int byteo = nl * 256 + ((ml * 2) ^ ((nl & 7) << 4));
        *(unsigned long long*)(pld + byteo) = pwu[sub];
      }
    };

    loadK(0, kAh, kAl);
    estep(kAh, kAl);
    pwrite(0);
    loadK(1, kAh, kAl);

#pragma unroll 1
    for (int it = 0; it < 32; ++it) {
      bf16x8 kBh[4], kBl[4];
      loadK((it + 2) & 31, kBh, kBl);
      if (it < 31) estep(kAh, kAl);
      SBAR();
      if (it < 31) pwrite((it + 1) & 1);
#pragma unroll
      for (int sub = 0; sub < 4; ++sub) { kAh[sub] = kBh[sub]; kAl[sub] = kBl[sub]; }
    }
  } else {
    // ======================= CONSUMER (r16 verbatim) =======================
    const int cw = w - 8;   // 32-c slice; also owns 8 attn rows [cw*8, cw*8+8)
    f32x4 acc[2][4];   // c = cw*32 + ct*16 + l4*4 + j ; n = n0 + nt*16 + l15
#pragma unroll
    for (int ct = 0; ct < 2; ++ct)
#pragma unroll
      for (int nt = 0; nt < 4; ++nt) acc[ct][nt] = f32x4{0.f, 0.f, 0.f, 0.f};

    bf16x8 vf[2][4];
    auto vload = [&](int chunk) {
#pragma unroll
      for (int ct = 0; ct < 2; ++ct)
#pragma unroll
        for (int ms = 0; ms < 4; ++ms) {
          size_t vo = (size_t)(chunk * 4 + ms) * 8192 +
                      (size_t)(cw * 32 + ct * 16 + l15) * 32 + l4 * 8;
          vf[ct][ms] = *(const bf16x8*)(vbb + vo);
        }
    };
    vload(0);

#pragma unroll 1
    for (int it = 0; it < 32; ++it) {
      SBAR();
      const int mb = it * 128;
      char* pl = (char*)p_lds[it & 1];
      __builtin_amdgcn_s_setprio(1);
#pragma unroll
      for (int ms = 0; ms < 4; ++ms) {
        int mbyte = ms * 64 + l4 * 16;
        bf16x8 pf[4];
#pragma unroll
        for (int nt = 0; nt < 4; ++nt) {
          int nl = nt * 16 + l15;
          pf[nt] = *(const bf16x8*)(pl + nl * 256 + (mbyte ^ ((nl & 7) << 4)));
        }
#pragma unroll
        for (int ct = 0; ct < 2; ++ct)
#pragma unroll
          for (int nt = 0; nt < 4; ++nt)
            acc[ct][nt] = MFMA16(vf[ct][ms], pf[nt], acc[ct][nt]);
      }
      __builtin_amdgcn_s_setprio(0);
      if (it < 31) vload(it + 1);   // slack = rest of iter + producer E-phase
      // attention store from LDS: rows [cw*8, cw*8+8), all 128 m of this
      // chunk. Per store: 2 rows x full 128B line. Issued AFTER the vloads.
#pragma unroll
      for (int s = 0; s < 4; ++s) {
        int row = cw * 8 + s * 2 + (l >> 5);
        int mcol = (l & 31) * 4;
        int byteo = row * 256 + ((mcol * 2) ^ ((row & 7) << 4));
        unsigned long long v64 = *(const unsigned long long*)(pl + byteo);
        f32x4 pv;
#pragma unroll
        for (int i = 0; i < 4; ++i)
          pv[i] = bf2f((short)(unsigned short)(v64 >> (16 * i)));
        __builtin_nontemporal_store(pv,
            (f32x4*)(attn + (size_t)row * NNq + mb + mcol));
      }
    }

    // epilogue: weighted = gamma*pv ; final = weighted + x
    const float gm = gamma[0];
#pragma unroll
    for (int ct = 0; ct < 2; ++ct) {
#pragma unroll
      for (int nt = 0; nt < 4; ++nt) {
#pragma unroll
        for (int j = 0; j < 4; ++j) {
          int c = cw * 32 + ct * 16 + l4 * 4 + j;
          int n = n0 + nt * 16 + l15;
          size_t go = ((size_t)b * CC + c) * NNq + n;
          float o = acc[ct][nt][j] * gm;
          out[4194304 + go] = o;
          out[go] = o + x[go];
        }
      }
    }
  }
}

extern "C" void kernel_launch(void* const* d_in, const int* in_sizes, int n_in,
                              void* d_out, int out_size, void* d_ws, size_t ws_size,
                              hipStream_t stream) {
  const float* x     = (const float*)d_in[0];
  const float* Wq    = (const float*)d_in[1];
  const float* bq    = (const float*)d_in[2];
  const float* Wk    = (const float*)d_in[3];
  const float* bk    = (const float*)d_in[4];
  const float* Wv    = (const float*)d_in[5];
  const float* bv    = (const float*)d_in[6];
  const float* gamma = (const float*)d_in[7];
  float* out = (float*)d_out;

  char* ws = (char*)d_ws;
  unsigned short* qh   = (unsigned short*)(ws);                    // 1 MB
  unsigned short* ql   = (unsigned short*)(ws + (1u << 20));       // 1 MB
  unsigned short* kh   = (unsigned short*)(ws + (2u << 20));       // 1 MB
  unsigned short* kl   = (unsigned short*)(ws + (3u << 20));       // 1 MB
  unsigned short* v5   = (unsigned short*)(ws + (4u << 20));       // 8 MB

  proj_kernel<<<256, 256, 0, stream>>>(x, Wq, bq, Wk, bk, Wv, bv, qh, ql, kh, kl, v5);
  attn_pv_kernel<<<256, 1024, 0, stream>>>(qh, ql, kh, kl, v5, x, gamma, out);
}